// Round 6
// baseline (386.880 us; speedup 1.0000x reference)
//
#include <hip/hip_runtime.h>

// FeatureExtractor via MFMA bf16 hi/lo, TRANSPOSED orientation.
// R6: 3-WAVE blocks — producer + TWO consumers splitting the recurrent work
// by gate tile. The serial h(t)->h(t+1) chain was owned by one wave (R5:
// ~2890 cy/step wall vs ~800 cy issue, VALUBusy 51% => latency-bound);
// splitting tiles 0-15 / 16-24 across C0/C1 halves the per-step serial
// issue (esp. the 48 quarter-rate transcendentals -> 24/wave) and raises
// occupancy 2->3 waves/SIMD.
//  wave 0 (producer): gx(t) -> ring slot t&3 (vector x load, proj MFMA,
//      LeakyReLU, p LDS exchange, 18 ih-MFMAs). Unchanged from R5.
//  wave 1 (C0): tile 0: 9 hh-MFMAs + nonlin + h write units 0-15.
//  wave 2 (C1): tile 1: 9 hh-MFMAs + nonlin + h write units 16-24.
// Handshake: monotone LDS counters s_prod/s_c0/s_c1; each consumer waits
// for the other's step t-1 before reading h(t) (h is fully in LDS).
// Ring relayout [slot][6][64] f32x4: lane stride 16B = canonical
// conflict-free pattern (R5's [slot][64][6] had 96B lane stride -> 16-way
// conflicts, SQ_LDS_BANK_CONFLICT 11.7M). Single base + 4KB-plane
// immediates retained. MFMA order per output element identical -> numerics
// bit-identical to R5.
//
// Layouts per verified guide mapping: A[m][k]/B[k][n]: m|n=lane&15,
// k=(lane>>4)*8+j; D: col=lane&15, row=(lane>>4)*4+reg.

typedef __bf16 bf16x8 __attribute__((ext_vector_type(8)));
typedef float  f32x4  __attribute__((ext_vector_type(4)));

#define TT 128
#define CC 25
#define PP 20
#define HH 25
#define NSEQ 16384
#define S  36          // LDS row stride (floats) for sp/sh
#define MFMA __builtin_amdgcn_mfma_f32_16x16x32_bf16
#define LD_ACQ(p)    __hip_atomic_load((p), __ATOMIC_ACQUIRE, __HIP_MEMORY_SCOPE_WORKGROUP)
#define ST_REL(p, v) __hip_atomic_store((p), (v), __ATOMIC_RELEASE, __HIP_MEMORY_SCOPE_WORKGROUP)

__device__ __forceinline__ void split2(float f, __bf16& hi, __bf16& lo) {
    hi = (__bf16)f;
    lo = (__bf16)(f - (float)hi);
}
__device__ __forceinline__ float frcp(float v) { return __builtin_amdgcn_rcpf(v); }

__global__ __launch_bounds__(192, 3) void gru_3w(
    const float* __restrict__ x,   const float* __restrict__ W1,
    const float* __restrict__ b1,  const float* __restrict__ Wih,
    const float* __restrict__ Whh, const float* __restrict__ bih,
    const float* __restrict__ bhh, float* __restrict__ out)
{
    __shared__ float sp[16 * S];            // producer: p rows, ch20 = 1.0
    __shared__ float sh[2][16 * S];         // h rows: ch0-24 h, ch25 = 1.0
    __shared__ f32x4 sgx[4][6][64];         // ring [slot][vec][lane], 16B/lane
    __shared__ int s_prod, s_c0, s_c1;      // monotone step counters

    const int tid  = threadIdx.x;
    const int wid  = tid >> 6;              // 0 producer, 1 C0, 2 C1
    const int lane = tid & 63;
    const int m = lane & 15, q = lane >> 4;
    const int n0 = blockIdx.x * 16;

    // ---- LDS init: zeros + bias channels + flags ----
    for (int idx = tid; idx < 16 * S; idx += 192) {
        sp[idx] = 0.f; sh[0][idx] = 0.f; sh[1][idx] = 0.f;
    }
    if (tid == 0) { s_prod = 0; s_c0 = 0; s_c1 = 0; }
    __syncthreads();
    if (tid < 16) {
        sp[tid * S + PP]    = 1.0f;
        sh[0][tid * S + HH] = 1.0f;
        sh[1][tid * S + HH] = 1.0f;
    }
    __syncthreads();

    if (wid == 0) {
        // ================= PRODUCER =================
        // Wih 6 tile-pairs (bias at k==PP) + W1 2 tile-pairs (bias at k==CC)
        bf16x8 WgH[6], WgL[6], WpH[2], WpL[2];
        #pragma unroll
        for (int tt = 0; tt < 6; ++tt) {
            const int g = tt >> 1;
            const int u = (tt & 1) * 16 + m;
            const bool uv = (u < HH);
            const int row = g * HH + u;
            bf16x8 h8, l8;
            #pragma unroll
            for (int j = 0; j < 8; ++j) {
                const int k = q * 8 + j;
                float v = 0.f;
                if (uv) {
                    if (k < PP)       v = Wih[row * PP + k];
                    else if (k == PP) v = bih[row];
                }
                __bf16 a, b; split2(v, a, b); h8[j] = a; l8[j] = b;
            }
            WgH[tt] = h8; WgL[tt] = l8;
        }
        #pragma unroll
        for (int tt = 0; tt < 2; ++tt) {
            const int u = tt * 16 + m;
            const bool uv = (u < PP);
            bf16x8 h8, l8;
            #pragma unroll
            for (int j = 0; j < 8; ++j) {
                const int k = q * 8 + j;
                float v = 0.f;
                if (uv) {
                    if (k < CC)       v = W1[u * CC + k];
                    else if (k == CC) v = b1[u];
                }
                __bf16 a, b; split2(v, a, b); h8[j] = a; l8[j] = b;
            }
            WpH[tt] = h8; WpL[tt] = l8;
        }

        const float* xrow = x + (size_t)(n0 + m) * (TT * CC);
        const int cbase = (q < 3) ? q * 8 : 21;   // q==3: backward-shifted x4
        float xc[8];

        auto load_x = [&](int t) {
            const float* xr = xrow + t * CC;
            f32x4 va = *(const f32x4*)(xr + cbase);
            f32x4 vb = *(const f32x4*)(xr + cbase + ((q < 3) ? 4 : 0));
            #pragma unroll
            for (int j = 0; j < 8; ++j) {
                float v;
                if (q < 3) v = (j < 4) ? va[j] : vb[j - 4];
                else       v = (j == 0) ? va[3] : (j == 1 ? 1.0f : 0.0f);
                xc[j] = v;
            }
        };

        auto produce = [&](int tc, int slot) {      // slot == tc&3, literal
            bf16x8 xH, xL;
            #pragma unroll
            for (int j = 0; j < 8; ++j) { __bf16 a,b; split2(xc[j],a,b); xH[j]=a; xL[j]=b; }

            {   // prefetch next x; in flight across the rest of this step
                const int tn = (tc + 1 < TT) ? tc + 1 : TT - 1;
                load_x(tn);
            }

            // proj: P[unit][seq] = W1aug * [x;1]  (3-term hi/lo, same order)
            f32x4 p0 = {0.f,0.f,0.f,0.f}, p1 = {0.f,0.f,0.f,0.f};
            p0 = MFMA(WpH[0], xH, p0, 0,0,0);
            p0 = MFMA(WpH[0], xL, p0, 0,0,0);
            p0 = MFMA(WpL[0], xH, p0, 0,0,0);
            p1 = MFMA(WpH[1], xH, p1, 0,0,0);
            p1 = MFMA(WpH[1], xL, p1, 0,0,0);
            p1 = MFMA(WpL[1], xH, p1, 0,0,0);
            #pragma unroll
            for (int r = 0; r < 4; ++r) {
                p0[r] = (p0[r] >= 0.f) ? p0[r] : 0.01f * p0[r];
                p1[r] = (p1[r] >= 0.f) ? p1[r] : 0.01f * p1[r];
            }

            // p -> LDS exchange (in-wave, producer-private)
            *(f32x4*)(sp + m * S + 4 * q) = p0;
            if (q == 0) *(f32x4*)(sp + m * S + 16) = p1;

            f32x4 pa = ((const f32x4*)(sp + m * S + 8 * q))[0];
            f32x4 pb = ((const f32x4*)(sp + m * S + 8 * q))[1];
            bf16x8 pH, pL;
            #pragma unroll
            for (int j = 0; j < 4; ++j) {
                __bf16 a, b;
                split2(pa[j], a, b); pH[j]   = a; pL[j]   = b;
                split2(pb[j], a, b); pH[4+j] = a; pL[4+j] = b;
            }

            // ih gate pre-activations -> ring slot (vec-major, conflict-free)
            f32x4* ring = &sgx[slot][0][lane];     // plane stride 64 f32x4 = 4KB
            #pragma unroll
            for (int tp = 0; tp < 2; ++tp) {
                f32x4 acc = {0.f,0.f,0.f,0.f};
                acc = MFMA(WgH[tp], pH, acc, 0,0,0);
                acc = MFMA(WgH[tp], pL, acc, 0,0,0);
                acc = MFMA(WgL[tp], pH, acc, 0,0,0);
                ring[(0 + tp) * 64] = acc;
                f32x4 az = {0.f,0.f,0.f,0.f};
                az = MFMA(WgH[2+tp], pH, az, 0,0,0);
                az = MFMA(WgH[2+tp], pL, az, 0,0,0);
                az = MFMA(WgL[2+tp], pH, az, 0,0,0);
                ring[(2 + tp) * 64] = az;
                f32x4 an = {0.f,0.f,0.f,0.f};
                an = MFMA(WgH[4+tp], pH, an, 0,0,0);
                an = MFMA(WgH[4+tp], pL, an, 0,0,0);
                an = MFMA(WgL[4+tp], pH, an, 0,0,0);
                ring[(4 + tp) * 64] = an;
            }
        };

        load_x(0);
        int kc0 = 0, kc1 = 0;
        for (int tb = 0; tb < TT; tb += 4) {
            #pragma unroll
            for (int u4 = 0; u4 < 4; ++u4) {
                const int t = tb + u4;
                // slot u4 consumed (both tiles) at step t-4 -> counters >= t-3
                if (t >= 4) {
                    if (kc0 < t - 3) do { kc0 = LD_ACQ(&s_c0); } while (kc0 < t - 3);
                    if (kc1 < t - 3) do { kc1 = LD_ACQ(&s_c1); } while (kc1 < t - 3);
                }
                produce(t, u4);
                if (lane == 0) ST_REL(&s_prod, t + 1);
            }
        }
    } else {
        // ================= CONSUMER (tile ctp) =================
        const bool c0 = (wid == 1);
        const int ctp = wid - 1;                   // wave-uniform tile index
        // Whh 3 named pairs for this tile (bias at k==HH)
        bf16x8 WrH, WrL, WzH, WzL, WnH, WnL;
        {
            const int u = ctp * 16 + m;
            const bool uv = (u < HH);
            #pragma unroll
            for (int g = 0; g < 3; ++g) {
                const int row = g * HH + u;
                bf16x8 h8, l8;
                #pragma unroll
                for (int j = 0; j < 8; ++j) {
                    const int k = q * 8 + j;
                    float v = 0.f;
                    if (uv) {
                        if (k < HH)       v = Whh[row * HH + k];
                        else if (k == HH) v = bhh[row];
                    }
                    __bf16 a, b; split2(v, a, b); h8[j] = a; l8[j] = b;
                }
                if (g == 0)      { WrH = h8; WrL = l8; }
                else if (g == 1) { WzH = h8; WzL = l8; }
                else             { WnH = h8; WnL = l8; }
            }
        }

        float ho[4] = {0.f, 0.f, 0.f, 0.f};
        int* other = c0 ? &s_c1 : &s_c0;
        int* own   = c0 ? &s_c0 : &s_c1;
        int kp = 0, ko = 0;

        for (int tb = 0; tb < TT; tb += 4) {
            #pragma unroll
            for (int u4 = 0; u4 < 4; ++u4) {
                const int t = tb + u4;              // parity t&1 == u4&1
                if (kp < t + 1) do { kp = LD_ACQ(&s_prod); } while (kp < t + 1);
                if (ko < t)     do { ko = LD_ACQ(other);   } while (ko < t);

                const float* hrow = sh[u4 & 1] + m * S + 8 * q;
                f32x4 ha = ((const f32x4*)hrow)[0];
                f32x4 hb = ((const f32x4*)hrow)[1];
                bf16x8 hH, hL;
                #pragma unroll
                for (int j = 0; j < 4; ++j) {
                    __bf16 a, b;
                    split2(ha[j], a, b); hH[j]   = a; hL[j]   = b;
                    split2(hb[j], a, b); hH[4+j] = a; hL[4+j] = b;
                }
                // ring seeds for this tile: planes ctp, 2+ctp, 4+ctp
                const f32x4* rc = &sgx[u4][ctp][lane];
                f32x4 aRv = rc[0];                    // = ih terms, same order
                aRv = MFMA(WrH, hH, aRv, 0,0,0);
                aRv = MFMA(WrH, hL, aRv, 0,0,0);
                aRv = MFMA(WrL, hH, aRv, 0,0,0);
                f32x4 aZv = rc[128];
                aZv = MFMA(WzH, hH, aZv, 0,0,0);
                aZv = MFMA(WzH, hL, aZv, 0,0,0);
                aZv = MFMA(WzL, hH, aZv, 0,0,0);
                f32x4 gNv = rc[256];
                f32x4 aHv = {0.f,0.f,0.f,0.f};
                aHv = MFMA(WnH, hH, aHv, 0,0,0);
                aHv = MFMA(WnH, hL, aHv, 0,0,0);
                aHv = MFMA(WnL, hH, aHv, 0,0,0);

                f32x4 hv;
                #pragma unroll
                for (int r = 0; r < 4; ++r) {
                    const float rg = frcp(1.f + __expf(-aRv[r]));
                    const float zg = frcp(1.f + __expf(-aZv[r]));
                    const float nv = gNv[r] + rg * aHv[r];
                    const float e  = __expf(-2.f * nv);
                    const float ng = 2.f * frcp(1.f + e) - 1.f;      // tanh
                    const float h2 = zg * (ho[r] - ng) + ng;         // (1-z)n + z h
                    ho[r] = h2; hv[r] = h2;
                }
                float* dst = sh[(u4 & 1) ^ 1] + m * S + ctp * 16 + 4 * q;
                if (c0) {
                    *(f32x4*)dst = hv;                  // units 0-15
                } else {
                    if (q < 2)       *(f32x4*)dst = hv; // units 16-23
                    else if (q == 2) dst[0] = hv[0];    // unit 24
                }
                if (lane == 0) ST_REL(own, t + 1);
            }
        }

        // ---- epilogue: out[seq][unit], each consumer its tile ----
        float* orow = out + (size_t)(n0 + m) * HH;
        #pragma unroll
        for (int r = 0; r < 4; ++r) {
            const int u = ctp * 16 + 4 * q + r;
            if (u < HH) orow[u] = ho[r];
        }
    }
}

extern "C" void kernel_launch(void* const* d_in, const int* in_sizes, int n_in,
                              void* d_out, int out_size, void* d_ws, size_t ws_size,
                              hipStream_t stream) {
    const float* x   = (const float*)d_in[0];
    const float* W1  = (const float*)d_in[1];
    const float* b1  = (const float*)d_in[2];
    const float* Wih = (const float*)d_in[3];
    const float* Whh = (const float*)d_in[4];
    const float* bih = (const float*)d_in[5];
    const float* bhh = (const float*)d_in[6];
    float* out = (float*)d_out;

    gru_3w<<<NSEQ / 16, 192, 0, stream>>>(x, W1, b1, Wih, Whh, bih, bhh, out);
}